// Round 13
// baseline (294.596 us; speedup 1.0000x reference)
//
#include <hip/hip_runtime.h>
#include <stdint.h>

// Problem constants
#define B_    16
#define C_    1024
#define H_    4096
#define T_    512
#define HT    (H_*T_)        // 2097152 = 2^21
#define KSP   128            // K_SPARSE
#define NBINS 4096
#define KEY_LO   (-8.0f)
#define KEY_INVW (204.8f)    // NBINS / 20.0
#define MARGIN   64          // safety bins below threshold (covers bf16 + bf16-GEMM error)
#define CAP      4096        // candidate cap per batch
#define ZQ    5248           // float4 slices of d_out zeroed per gemm block (2048*5248*16 = 171,966,464)

typedef __bf16 bf16x8 __attribute__((ext_vector_type(8)));
typedef float  f32x4  __attribute__((ext_vector_type(4)));
typedef int    i32x4  __attribute__((ext_vector_type(4)));
typedef unsigned int u32x4 __attribute__((ext_vector_type(4)));

static __device__ __forceinline__ unsigned short f2bf(float f) {
  union { float f; uint32_t u; } v; v.f = f;
  uint32_t u = v.u;
  return (unsigned short)((u + 0x7FFFu + ((u >> 16) & 1u)) >> 16); // RNE
}
static __device__ __forceinline__ float bf2f(unsigned short s) {
  union { uint32_t u; float f; } v; v.u = ((uint32_t)s) << 16;
  return v.f;
}
static __device__ __forceinline__ int key_bin(float kf) {
  float b = (kf - KEY_LO) * KEY_INVW;
  b = fminf(fmaxf(b, 0.0f), 4095.0f);
  return (int)b;
}
static __device__ __forceinline__ void async_load16(const void* g, void* l) {
  __builtin_amdgcn_global_load_lds((const __attribute__((address_space(1))) void*)g,
                                   (__attribute__((address_space(3))) void*)l, 16, 0, 0);
}
// non-temporal 16B zero store: zeros are never re-read on device -> keep them out of L2
static __device__ __forceinline__ void nt_zero16(float4* p) {
  i32x4 z = (i32x4){0, 0, 0, 0};
  __builtin_nontemporal_store(z, (i32x4*)p);
}
// non-temporal 16B load (read-once streams)
static __device__ __forceinline__ u32x4 nt_load16(const void* p) {
  return __builtin_nontemporal_load((const u32x4*)p);
}
// order-isomorphic double <-> uint64 (larger double => larger u64)
static __device__ __forceinline__ unsigned long long d2u(double d) {
  union { double d; unsigned long long u; } v; v.d = d;
  unsigned long long u = v.u;
  return (u >> 63) ? ~u : (u | 0x8000000000000000ull);
}
static __device__ __forceinline__ double u2d(unsigned long long s) {
  union { unsigned long long u; double d; } v;
  v.u = (s >> 63) ? (s & 0x7FFFFFFFFFFFFFFFull) : ~s;
  return v.d;
}

// ---------- P0: fused {weight convert x2, x transpose, ghist/cnt zero} ----------
__global__ void k_pre(const float* __restrict__ x, const float* __restrict__ wup,
                      const float* __restrict__ wsal,
                      unsigned short* __restrict__ wup16, unsigned short* __restrict__ wsal16,
                      float* __restrict__ xT32, unsigned short* __restrict__ xT16,
                      unsigned int* __restrict__ gzero) {
  int bid = blockIdx.x; int tid = threadIdx.x;
  __shared__ float tile[64][65];
  if (bid < 8192) {          // weight convert: 2*1048576 float4
    int i = bid * 256 + tid;
    int n4 = (H_ * C_) / 4;
    const float* src; unsigned short* dst; int j;
    if (i < n4) { src = wup; dst = wup16; j = i; }
    else        { src = wsal; dst = wsal16; j = i - n4; }
    float4 v = ((const float4*)src)[j];
    ushort4 o; o.x = f2bf(v.x); o.y = f2bf(v.y); o.z = f2bf(v.z); o.w = f2bf(v.w);
    ((ushort4*)dst)[j] = o;
    return;
  }
  if (bid < 8192 + 2048) {   // transpose x (B,C,T) -> (B,T,C) f32+bf16
    int r  = bid - 8192;
    int b  = r >> 7;
    int c0 = ((r >> 3) & 15) * 64;
    int t0 = (r & 7) * 64;
    int tt = tid & 63;
    int g  = tid >> 6;
    const float* xb = x + (size_t)b * C_ * T_;
    #pragma unroll
    for (int it = 0; it < 16; ++it) {
      int cl = g + it * 4;
      tile[cl][tt] = xb[(size_t)(c0 + cl) * T_ + t0 + tt];
    }
    __syncthreads();
    float* oT = xT32 + (size_t)b * T_ * C_;
    unsigned short* oH = xT16 + (size_t)b * T_ * C_;
    #pragma unroll
    for (int it = 0; it < 16; ++it) {
      int tl = g + it * 4;
      float v = tile[tt][tl];
      oT[(size_t)(t0 + tl) * C_ + c0 + tt] = v;
      oH[(size_t)(t0 + tl) * C_ + c0 + tt] = f2bf(v);
    }
    return;
  }
  // zero ghist (65536 u32) + cnt/theta/M/S region (pad to 65552)
  int w = (bid - 10240) * 256 + tid;
  if (w < 65552) gzero[w] = 0;
}

// ---------- Pass A: fused dual GEMM + key + histogram + softmax partials ----------
// R7-exact core + NT d_out zeroing issued AFTER the barrier (off the vmcnt-drain
// critical path: stores retire under the following MFMA + next stage).
__launch_bounds__(256, 2)
__global__ void k_gemm(const unsigned short* __restrict__ wup16,
                       const unsigned short* __restrict__ wsal16,
                       const unsigned short* __restrict__ xT16,
                       const float* __restrict__ up_b,
                       const float* __restrict__ sal_b,
                       unsigned char* __restrict__ keys8,
                       float2* __restrict__ partials,
                       unsigned int* __restrict__ ghist,
                       float4* __restrict__ zb_all) {
  int b     = blockIdx.y;
  int tileH = blockIdx.x >> 2;     // 0..31
  int tileT = blockIdx.x & 3;      // 0..3
  int tid  = threadIdx.x;
  int lane = tid & 63, wave = tid >> 6;
  int waveR = wave >> 1, waveC = wave & 1;

  __shared__ __align__(16) char smem[49152];   // Aup | Asal | B (each 128x64 bf16 = 16KB)
  __shared__ float redA[4], redB[4];
  char* sA = smem;
  char* sS = smem + 16384;
  char* sB = smem + 32768;

  float4* zb = zb_all ? (zb_all + (size_t)(b * 128 + blockIdx.x) * ZQ) : (float4*)0;

  f32x4 accU[4][4], accS[4][4];
  #pragma unroll
  for (int m = 0; m < 4; ++m)
    #pragma unroll
    for (int n = 0; n < 4; ++n) { accU[m][n] = (f32x4){0,0,0,0}; accS[m][n] = (f32x4){0,0,0,0}; }

  // Staging: linear LDS dest; source chunk pre-swizzled (rule 21 / T2).
  int srcChunk = (lane & 7) ^ (lane >> 3);
  const unsigned short* gA[4]; const unsigned short* gS[4]; const unsigned short* gB[4];
  #pragma unroll
  for (int j = 0; j < 4; ++j) {
    int r = j * 32 + wave * 8 + (lane >> 3);      // tile row 0..127
    gA[j] = wup16  + (size_t)(tileH * 128 + r) * C_ + srcChunk * 8;
    gS[j] = wsal16 + (size_t)(tileH * 128 + r) * C_ + srcChunk * 8;
    gB[j] = xT16   + (size_t)b * T_ * C_ + (size_t)(tileT * 128 + r) * C_ + srcChunk * 8;
  }
  int rowL = lane & 15;
  int fragChunk = (lane >> 4) * 16;   // byte offset of this lane's k-slice
  int swz = (lane & 7) << 4;

  for (int step = 0; step < 16; ++step) {
    int k0 = step * 64;
    #pragma unroll
    for (int j = 0; j < 4; ++j) {
      char* la = sA + j * 4096 + wave * 1024;
      char* ls = sS + j * 4096 + wave * 1024;
      char* lb = sB + j * 4096 + wave * 1024;
      async_load16(gA[j] + k0, la);
      async_load16(gS[j] + k0, ls);
      async_load16(gB[j] + k0, lb);
    }
    __syncthreads();
    // output zeroing AFTER the barrier: stores drain under MFMA + next stage,
    // not under this step's vmcnt(0) barrier wait.
    if (zb) {
      if (step < 10) {
        nt_zero16(&zb[step * 512 + tid]);
        nt_zero16(&zb[step * 512 + 256 + tid]);
      } else if (step == 10 && tid < 128) {
        nt_zero16(&zb[5120 + tid]);
      }
    }
    #pragma unroll
    for (int ksub = 0; ksub < 2; ++ksub) {
      int kb = ksub * 64 + fragChunk;            // 0..112, bits 4..6
      bf16x8 bf[4];
      #pragma unroll
      for (int n = 0; n < 4; ++n) {
        int row = waveC * 64 + n * 16 + rowL;
        bf[n] = *(const bf16x8*)(sB + row * 128 + (kb ^ swz));
      }
      #pragma unroll
      for (int m = 0; m < 4; ++m) {
        int row = waveR * 64 + m * 16 + rowL;
        bf16x8 au = *(const bf16x8*)(sA + row * 128 + (kb ^ swz));
        bf16x8 as = *(const bf16x8*)(sS + row * 128 + (kb ^ swz));
        #pragma unroll
        for (int n = 0; n < 4; ++n) {
          accU[m][n] = __builtin_amdgcn_mfma_f32_16x16x32_bf16(au, bf[n], accU[m][n], 0, 0, 0);
          accS[m][n] = __builtin_amdgcn_mfma_f32_16x16x32_bf16(as, bf[n], accS[m][n], 0, 0, 0);
        }
      }
    }
    __syncthreads();
  }

  // Epilogue: biases
  int hb = tileH * 128 + waveR * 64;
  int tb = tileT * 128 + waveC * 64;
  int colL  = lane & 15;
  int rowHi = (lane >> 4) * 4;
  #pragma unroll
  for (int m = 0; m < 4; ++m)
    #pragma unroll
    for (int r = 0; r < 4; ++r) {
      int h = hb + m * 16 + rowHi + r;
      float ub = up_b[h], sb = sal_b[h];
      #pragma unroll
      for (int n = 0; n < 4; ++n) { accU[m][n][r] += ub; accS[m][n][r] += sb; }
    }

  // Block max of sal
  float lm = -INFINITY;
  #pragma unroll
  for (int m = 0; m < 4; ++m)
    #pragma unroll
    for (int n = 0; n < 4; ++n)
      #pragma unroll
      for (int r = 0; r < 4; ++r) lm = fmaxf(lm, accS[m][n][r]);
  for (int o = 32; o; o >>= 1) lm = fmaxf(lm, __shfl_xor(lm, o));
  if (lane == 0) redA[wave] = lm;
  __syncthreads();
  float M = fmaxf(fmaxf(redA[0], redA[1]), fmaxf(redA[2], redA[3]));
  float ls = 0.0f;
  #pragma unroll
  for (int m = 0; m < 4; ++m)
    #pragma unroll
    for (int n = 0; n < 4; ++n)
      #pragma unroll
      for (int r = 0; r < 4; ++r) ls += __expf(accS[m][n][r] - M);
  for (int o = 32; o; o >>= 1) ls += __shfl_xor(ls, o);
  if (lane == 0) redB[wave] = ls;
  __syncthreads();
  if (tid == 0)
    partials[b * 128 + blockIdx.x] = make_float2(M, redB[0] + redB[1] + redB[2] + redB[3]);

  // Histogram of bf16-rounded keys (reuse tile LDS); store u8 coarse bin
  unsigned int* hist = (unsigned int*)smem;
  for (int i = tid; i < NBINS; i += 256) hist[i] = 0;
  __syncthreads();
  unsigned char* keysB = keys8 + (size_t)b * HT;
  #pragma unroll
  for (int m = 0; m < 4; ++m)
    #pragma unroll
    for (int n = 0; n < 4; ++n)
      #pragma unroll
      for (int r = 0; r < 4; ++r) {
        float sig = accU[m][n][r];
        float sal = accS[m][n][r];
        float key = (sig > 0.0f) ? (__logf(sig) + sal) : -INFINITY;
        unsigned short kb16 = f2bf(key);
        int bin = key_bin(bf2f(kb16));
        int h = hb + m * 16 + rowHi + r;
        int t = tb + n * 16 + colL;
        keysB[(size_t)h * T_ + t] = (unsigned char)(bin >> 4);
        atomicAdd(&hist[bin], 1u);
      }
  __syncthreads();
  unsigned int* gh = ghist + b * NBINS;
  for (int i = tid; i < NBINS; i += 256) {
    unsigned int cv = hist[i];
    if (cv) atomicAdd(&gh[i], cv);
  }
}

// ---------- Pass B: per-batch M/S reduce + histogram threshold (parallel) ----------
__global__ void k_reduce(const float2* __restrict__ partials,
                         const unsigned int* __restrict__ ghist,
                         float* __restrict__ Mv, float* __restrict__ Sv,
                         int* __restrict__ thetaBin) {
  int b = blockIdx.x; int tid = threadIdx.x; int lane = tid & 63;
  __shared__ float sm[128], ss[128];
  __shared__ unsigned int hloc[NBINS];
  __shared__ unsigned int segsum[256];
  __shared__ float redM[2], redS[2];
  if (tid < 128) { float2 p = partials[b * 128 + tid]; sm[tid] = p.x; ss[tid] = p.y; }
  const unsigned int* gh = ghist + b * NBINS;
  int hi = 4095 - 16 * tid;
  unsigned int seg = 0;
  #pragma unroll
  for (int k = 0; k < 16; ++k) { unsigned int c = gh[hi - k]; hloc[hi - k] = c; seg += c; }
  segsum[tid] = seg;
  __syncthreads();
  if (tid < 128) {
    float m = sm[tid];
    for (int o = 32; o; o >>= 1) m = fmaxf(m, __shfl_xor(m, o));
    if (lane == 0) redM[tid >> 6] = m;
  }
  __syncthreads();
  float M = fmaxf(redM[0], redM[1]);
  if (tid < 128) {
    float s = ss[tid] * __expf(sm[tid] - M);
    for (int o = 32; o; o >>= 1) s += __shfl_xor(s, o);
    if (lane == 0) redS[tid >> 6] = s;
  }
  __syncthreads();
  if (tid == 0) {
    Mv[b] = M; Sv[b] = redS[0] + redS[1];
    unsigned int acc = 0; int theta = 1; int sidx = 0;
    while (sidx < 256 && acc + segsum[sidx] < KSP) { acc += segsum[sidx]; ++sidx; }
    if (sidx < 256) {
      int h2 = 4095 - 16 * sidx;
      for (int k = 0; k < 16; ++k) {
        acc += hloc[h2 - k];
        if (acc >= KSP) { theta = h2 - k; break; }
      }
    }
    theta -= MARGIN; if (theta < 1) theta = 1;
    thetaBin[b] = theta;
  }
}

// ---------- Pass C: collect candidates from u8 bins (block scan + 1 atomic/block) ----------
__global__ void k_collect(const unsigned char* __restrict__ keys8,
                          const int* __restrict__ thetaBin,
                          unsigned int* __restrict__ cnt,
                          unsigned int* __restrict__ cand) {
  __shared__ unsigned int wtot[4], wbase[4];
  int tid = threadIdx.x;
  int lane = tid & 63, wave = tid >> 6;
  size_t blockBase = (size_t)blockIdx.x * 8192;
  int b = (int)(blockBase >> 21);
  unsigned int localBase = (unsigned int)(blockBase & (HT - 1));
  unsigned int thetaU8 = (unsigned int)(thetaBin[b] >> 4);
  const unsigned char* kb = keys8 + blockBase;

  // non-temporal: keys8 is a read-once stream; keep L2 for refine's inputs
  u32x4 v[2];
  #pragma unroll
  for (int j = 0; j < 2; ++j) v[j] = nt_load16(kb + j * 4096 + tid * 16);

  unsigned int mask = 0, mycnt = 0;
  #pragma unroll
  for (int j = 0; j < 2; ++j) {
    #pragma unroll
    for (int q = 0; q < 4; ++q) {
      unsigned int w = v[j][q];
      #pragma unroll
      for (int k = 0; k < 4; ++k) {
        unsigned int bv = (w >> (8 * k)) & 0xFFu;
        if (bv >= thetaU8) { mask |= 1u << (j * 16 + q * 4 + k); ++mycnt; }
      }
    }
  }

  unsigned int pre = mycnt;
  #pragma unroll
  for (int o = 1; o < 64; o <<= 1) {
    unsigned int t = __shfl_up(pre, o);
    if (lane >= o) pre += t;
  }
  unsigned int myExcl = pre - mycnt;
  if (lane == 63) wtot[wave] = pre;
  __syncthreads();
  if (tid == 0) {
    unsigned int tot = wtot[0] + wtot[1] + wtot[2] + wtot[3];
    unsigned int gbase = tot ? atomicAdd(&cnt[b], tot) : 0u;
    unsigned int acc = gbase;
    #pragma unroll
    for (int w = 0; w < 4; ++w) { wbase[w] = acc; acc += wtot[w]; }
  }
  __syncthreads();
  unsigned int pos = wbase[wave] + myExcl;
  unsigned int m = mask;
  while (m) {
    int i = __ffs(m) - 1; m &= m - 1;
    int j = i >> 4, rq = i & 15;
    unsigned int idx = localBase + (unsigned int)(j * 4096 + tid * 16 + rq);
    if (pos < CAP) cand[b * CAP + pos] = idx;
    ++pos;
  }
}

// ---------- Pass D1: exact fp64 recompute, one WAVE per candidate (no barriers) ----------
__global__ void k_refine(const float* __restrict__ xT32, const float* __restrict__ wup,
                         const float* __restrict__ wsal, const float* __restrict__ up_b,
                         const float* __restrict__ sal_b, const unsigned int* __restrict__ cnt,
                         const unsigned int* __restrict__ cand, double* __restrict__ keyd) {
  int b = blockIdx.y;
  unsigned int nc = cnt[b];
  int n = nc < CAP ? (int)nc : CAP;
  int lane = threadIdx.x & 63;
  int wid = blockIdx.x * 4 + (threadIdx.x >> 6);   // 0..511 waves per batch
  for (int slot = wid; slot < n; slot += 512) {
    unsigned int idx = cand[b * CAP + slot];
    int h = (int)(idx >> 9), t = (int)(idx & 511);
    const float4* wv = (const float4*)(wup  + (size_t)h * C_);
    const float4* sv = (const float4*)(wsal + (size_t)h * C_);
    const float4* xv = (const float4*)(xT32 + ((size_t)b * T_ + t) * C_);
    double du = 0.0, ds = 0.0;
    #pragma unroll
    for (int j = 0; j < 4; ++j) {
      float4 w4 = wv[lane + 64 * j];
      float4 s4 = sv[lane + 64 * j];
      float4 x4 = xv[lane + 64 * j];
      du += (double)w4.x * x4.x + (double)w4.y * x4.y + (double)w4.z * x4.z + (double)w4.w * x4.w;
      ds += (double)s4.x * x4.x + (double)s4.y * x4.y + (double)s4.z * x4.z + (double)s4.w * x4.w;
    }
    #pragma unroll
    for (int o = 32; o; o >>= 1) { du += __shfl_xor(du, o); ds += __shfl_xor(ds, o); }
    if (lane == 0) {
      double sig = du + (double)up_b[h];
      double sal = ds + (double)sal_b[h];
      keyd[b * CAP + slot] = (sig > 0.0) ? (log(sig) + sal) : -1e300;
    }
  }
}

// ---------- Pass D2: bitonic-sort top-128 selection + scatter outputs ----------
__launch_bounds__(256, 1)
__global__ void k_final(const double* __restrict__ keyd, const unsigned int* __restrict__ cnt,
                        const unsigned int* __restrict__ cand, const float* __restrict__ Mv,
                        const float* __restrict__ Sv, float* __restrict__ out) {
  int b = blockIdx.x; int tid = threadIdx.x;
  unsigned int nc = cnt[b];
  int n = nc < CAP ? (int)nc : CAP;
  int L = 256;
  while (L < n) L <<= 1;

  __shared__ unsigned long long sk[CAP];  // ~d2u(key): ascending sk == descending key
  __shared__ unsigned int sid[CAP];
  for (int i = tid; i < L; i += 256) {
    if (i < n) { sk[i] = ~d2u(keyd[b * CAP + i]); sid[i] = cand[b * CAP + i]; }
    else       { sk[i] = 0xFFFFFFFFFFFFFFFFull;   sid[i] = 0xFFFFFFFFu; }
  }
  for (int size = 2; size <= L; size <<= 1) {
    for (int stride = size >> 1; stride > 0; stride >>= 1) {
      __syncthreads();
      for (int i = tid; i < (L >> 1); i += 256) {
        int ix = 2 * i - (i & (stride - 1));
        int iy = ix + stride;
        bool asc = ((ix & size) == 0);
        unsigned long long ka = sk[ix], kb = sk[iy];
        unsigned int ia = sid[ix], ib = sid[iy];
        bool aLessB = (ka < kb) || (ka == kb && ia < ib);
        if (asc != aLessB) { sk[ix] = kb; sk[iy] = ka; sid[ix] = ib; sid[iy] = ia; }
      }
    }
  }
  __syncthreads();
  if (tid < KSP) {
    unsigned int idx = sid[tid];
    if (idx != 0xFFFFFFFFu) {
      double key = u2d(~sk[tid]);
      double val = exp(key - (double)Mv[b]) / (double)Sv[b];
      float vf = (float)val;
      int h = (int)(idx >> 9), t = (int)(idx & 511);
      out[(size_t)b * HT + idx] = vf;                                             // sparse
      out[(size_t)B_ * HT + ((size_t)b * KSP + tid) * H_ + h] = vf;               // packed
      out[(size_t)B_ * HT + (size_t)B_ * KSP * H_ + ((size_t)b * KSP + tid) * T_ + t] = 1.0f; // time_oh
    }
  }
}

extern "C" void kernel_launch(void* const* d_in, const int* in_sizes, int n_in,
                              void* d_out, int out_size, void* d_ws, size_t ws_size,
                              hipStream_t stream) {
  const float* x    = (const float*)d_in[0];
  const float* wup  = (const float*)d_in[1];
  const float* upb  = (const float*)d_in[2];
  const float* wsal = (const float*)d_in[3];
  const float* salb = (const float*)d_in[4];
  float* out = (float*)d_out;

  // Small scratch always at the front of d_ws.
  char* wb = (char*)d_ws;
  unsigned int* ghist  = (unsigned int*)wb;            // 262,144 B
  unsigned int* cnt    = (unsigned int*)(wb + 262144); // (ghist+cnt zeroed by k_pre)
  int*          thetaB = (int*)(wb + 262208);
  float*        Mv     = (float*)(wb + 262272);
  float*        Sv     = (float*)(wb + 262336);
  float2*       parts  = (float2*)(wb + 262400);       // 16,384 B
  unsigned int* cand   = (unsigned int*)(wb + 278784); // 262,144 B
  double*       keyd   = (double*)(wb + 540928);       // 524,288 B -> small region ends 1,065,216

  // Big scratch: in d_ws if it fits (then d_out is pure output, zeroed by k_gemm),
  // else inside d_out (R8 fallback, zeroed by memset after last scratch read).
  const size_t SMALL_END = 1065216;
  const size_t BIG_BYTES = 100663296;
  bool wsPath = (ws_size >= SMALL_END + BIG_BYTES);
  char* big = wsPath ? (wb + SMALL_END) : (char*)d_out;

  unsigned char*  keys8  = (unsigned char*)(big);                // 33,554,432 B
  float*          xT32   = (float*)(big + 33554432);             // 33,554,432 B
  unsigned short* xT16   = (unsigned short*)(big + 67108864);    // 16,777,216 B
  unsigned short* wup16  = (unsigned short*)(big + 83886080);    //  8,388,608 B
  unsigned short* wsal16 = (unsigned short*)(big + 92274688);    //  8,388,608 B (ends 100,663,296)

  k_pre<<<10497, 256, 0, stream>>>(x, wup, wsal, wup16, wsal16, xT32, xT16, ghist);
  k_gemm<<<dim3(128, B_), 256, 0, stream>>>(wup16, wsal16, xT16, upb, salb, keys8, parts, ghist,
                                            wsPath ? (float4*)d_out : (float4*)0);
  k_reduce<<<B_, 256, 0, stream>>>(parts, ghist, Mv, Sv, thetaB);
  k_collect<<<4096, 256, 0, stream>>>(keys8, thetaB, cnt, cand);
  k_refine<<<dim3(128, B_), 256, 0, stream>>>(xT32, wup, wsal, upb, salb, cnt, cand, keyd);
  if (!wsPath) { (void)hipMemsetAsync(d_out, 0, (size_t)out_size * 4, stream); }
  k_final<<<B_, 256, 0, stream>>>(keyd, cnt, cand, Mv, Sv, out);
}

// Round 14
// 291.763 us; speedup vs baseline: 1.0097x; 1.0097x over previous
//
#include <hip/hip_runtime.h>
#include <stdint.h>

// Problem constants
#define B_    16
#define C_    1024
#define H_    4096
#define T_    512
#define HT    (H_*T_)        // 2097152 = 2^21
#define KSP   128            // K_SPARSE
#define NBINS 4096
#define KEY_LO   (-8.0f)
#define KEY_INVW (204.8f)    // NBINS / 20.0
#define MARGIN   64          // safety bins below threshold (covers bf16 + bf16-GEMM error)
#define CAP      4096        // candidate cap per batch
#define ZQ    5248           // float4 slices of d_out zeroed per gemm block (2048*5248*16 = 171,966,464)

typedef __bf16 bf16x8 __attribute__((ext_vector_type(8)));
typedef float  f32x4  __attribute__((ext_vector_type(4)));
typedef int    i32x4  __attribute__((ext_vector_type(4)));

static __device__ __forceinline__ unsigned short f2bf(float f) {
  union { float f; uint32_t u; } v; v.f = f;
  uint32_t u = v.u;
  return (unsigned short)((u + 0x7FFFu + ((u >> 16) & 1u)) >> 16); // RNE
}
static __device__ __forceinline__ float bf2f(unsigned short s) {
  union { uint32_t u; float f; } v; v.u = ((uint32_t)s) << 16;
  return v.f;
}
static __device__ __forceinline__ int key_bin(float kf) {
  float b = (kf - KEY_LO) * KEY_INVW;
  b = fminf(fmaxf(b, 0.0f), 4095.0f);
  return (int)b;
}
static __device__ __forceinline__ void async_load16(const void* g, void* l) {
  __builtin_amdgcn_global_load_lds((const __attribute__((address_space(1))) void*)g,
                                   (__attribute__((address_space(3))) void*)l, 16, 0, 0);
}
// non-temporal 16B zero store: zeros are never re-read on device -> keep them out of L2
static __device__ __forceinline__ void nt_zero16(float4* p) {
  i32x4 z = (i32x4){0, 0, 0, 0};
  __builtin_nontemporal_store(z, (i32x4*)p);
}
// order-isomorphic double <-> uint64 (larger double => larger u64)
static __device__ __forceinline__ unsigned long long d2u(double d) {
  union { double d; unsigned long long u; } v; v.d = d;
  unsigned long long u = v.u;
  return (u >> 63) ? ~u : (u | 0x8000000000000000ull);
}
static __device__ __forceinline__ double u2d(unsigned long long s) {
  union { unsigned long long u; double d; } v;
  v.u = (s >> 63) ? (s & 0x7FFFFFFFFFFFFFFFull) : ~s;
  return v.d;
}

// ---------- P0: fused {weight convert x2, x transpose, ghist/cnt zero} ----------
__global__ void k_pre(const float* __restrict__ x, const float* __restrict__ wup,
                      const float* __restrict__ wsal,
                      unsigned short* __restrict__ wup16, unsigned short* __restrict__ wsal16,
                      float* __restrict__ xT32, unsigned short* __restrict__ xT16,
                      unsigned int* __restrict__ gzero) {
  int bid = blockIdx.x; int tid = threadIdx.x;
  __shared__ float tile[64][65];
  if (bid < 8192) {          // weight convert: 2*1048576 float4
    int i = bid * 256 + tid;
    int n4 = (H_ * C_) / 4;
    const float* src; unsigned short* dst; int j;
    if (i < n4) { src = wup; dst = wup16; j = i; }
    else        { src = wsal; dst = wsal16; j = i - n4; }
    float4 v = ((const float4*)src)[j];
    ushort4 o; o.x = f2bf(v.x); o.y = f2bf(v.y); o.z = f2bf(v.z); o.w = f2bf(v.w);
    ((ushort4*)dst)[j] = o;
    return;
  }
  if (bid < 8192 + 2048) {   // transpose x (B,C,T) -> (B,T,C) f32+bf16
    int r  = bid - 8192;
    int b  = r >> 7;
    int c0 = ((r >> 3) & 15) * 64;
    int t0 = (r & 7) * 64;
    int tt = tid & 63;
    int g  = tid >> 6;
    const float* xb = x + (size_t)b * C_ * T_;
    #pragma unroll
    for (int it = 0; it < 16; ++it) {
      int cl = g + it * 4;
      tile[cl][tt] = xb[(size_t)(c0 + cl) * T_ + t0 + tt];
    }
    __syncthreads();
    float* oT = xT32 + (size_t)b * T_ * C_;
    unsigned short* oH = xT16 + (size_t)b * T_ * C_;
    #pragma unroll
    for (int it = 0; it < 16; ++it) {
      int tl = g + it * 4;
      float v = tile[tt][tl];
      oT[(size_t)(t0 + tl) * C_ + c0 + tt] = v;
      oH[(size_t)(t0 + tl) * C_ + c0 + tt] = f2bf(v);
    }
    return;
  }
  // zero ghist (65536 u32) + cnt/theta/M/S region (pad to 65552)
  int w = (bid - 10240) * 256 + tid;
  if (w < 65552) gzero[w] = 0;
}

// ---------- Pass A: fused dual GEMM + key + histogram + softmax partials ----------
// R7-exact core + d_out zeroing via NON-TEMPORAL stores issued in the load-drain
// window (pre-barrier placement = best measured; post-barrier regressed, R13).
__launch_bounds__(256, 2)
__global__ void k_gemm(const unsigned short* __restrict__ wup16,
                       const unsigned short* __restrict__ wsal16,
                       const unsigned short* __restrict__ xT16,
                       const float* __restrict__ up_b,
                       const float* __restrict__ sal_b,
                       unsigned char* __restrict__ keys8,
                       float2* __restrict__ partials,
                       unsigned int* __restrict__ ghist,
                       float4* __restrict__ zb_all) {
  int b     = blockIdx.y;
  int tileH = blockIdx.x >> 2;     // 0..31
  int tileT = blockIdx.x & 3;      // 0..3
  int tid  = threadIdx.x;
  int lane = tid & 63, wave = tid >> 6;
  int waveR = wave >> 1, waveC = wave & 1;

  __shared__ __align__(16) char smem[49152];   // Aup | Asal | B (each 128x64 bf16 = 16KB)
  __shared__ float redA[4], redB[4];
  char* sA = smem;
  char* sS = smem + 16384;
  char* sB = smem + 32768;

  float4* zb = zb_all ? (zb_all + (size_t)(b * 128 + blockIdx.x) * ZQ) : (float4*)0;

  f32x4 accU[4][4], accS[4][4];
  #pragma unroll
  for (int m = 0; m < 4; ++m)
    #pragma unroll
    for (int n = 0; n < 4; ++n) { accU[m][n] = (f32x4){0,0,0,0}; accS[m][n] = (f32x4){0,0,0,0}; }

  // Staging: linear LDS dest; source chunk pre-swizzled (rule 21 / T2).
  int srcChunk = (lane & 7) ^ (lane >> 3);
  const unsigned short* gA[4]; const unsigned short* gS[4]; const unsigned short* gB[4];
  #pragma unroll
  for (int j = 0; j < 4; ++j) {
    int r = j * 32 + wave * 8 + (lane >> 3);      // tile row 0..127
    gA[j] = wup16  + (size_t)(tileH * 128 + r) * C_ + srcChunk * 8;
    gS[j] = wsal16 + (size_t)(tileH * 128 + r) * C_ + srcChunk * 8;
    gB[j] = xT16   + (size_t)b * T_ * C_ + (size_t)(tileT * 128 + r) * C_ + srcChunk * 8;
  }
  int rowL = lane & 15;
  int fragChunk = (lane >> 4) * 16;   // byte offset of this lane's k-slice
  int swz = (lane & 7) << 4;

  for (int step = 0; step < 16; ++step) {
    int k0 = step * 64;
    #pragma unroll
    for (int j = 0; j < 4; ++j) {
      char* la = sA + j * 4096 + wave * 1024;
      char* ls = sS + j * 4096 + wave * 1024;
      char* lb = sB + j * 4096 + wave * 1024;
      async_load16(gA[j] + k0, la);
      async_load16(gS[j] + k0, ls);
      async_load16(gB[j] + k0, lb);
    }
    // output zeroing, non-temporal, issued inside the load-drain window
    if (zb) {
      if (step < 10) {
        nt_zero16(&zb[step * 512 + tid]);
        nt_zero16(&zb[step * 512 + 256 + tid]);
      } else if (step == 10 && tid < 128) {
        nt_zero16(&zb[5120 + tid]);
      }
    }
    __syncthreads();
    #pragma unroll
    for (int ksub = 0; ksub < 2; ++ksub) {
      int kb = ksub * 64 + fragChunk;            // 0..112, bits 4..6
      bf16x8 bf[4];
      #pragma unroll
      for (int n = 0; n < 4; ++n) {
        int row = waveC * 64 + n * 16 + rowL;
        bf[n] = *(const bf16x8*)(sB + row * 128 + (kb ^ swz));
      }
      #pragma unroll
      for (int m = 0; m < 4; ++m) {
        int row = waveR * 64 + m * 16 + rowL;
        bf16x8 au = *(const bf16x8*)(sA + row * 128 + (kb ^ swz));
        bf16x8 as = *(const bf16x8*)(sS + row * 128 + (kb ^ swz));
        #pragma unroll
        for (int n = 0; n < 4; ++n) {
          accU[m][n] = __builtin_amdgcn_mfma_f32_16x16x32_bf16(au, bf[n], accU[m][n], 0, 0, 0);
          accS[m][n] = __builtin_amdgcn_mfma_f32_16x16x32_bf16(as, bf[n], accS[m][n], 0, 0, 0);
        }
      }
    }
    __syncthreads();
  }

  // Epilogue: biases
  int hb = tileH * 128 + waveR * 64;
  int tb = tileT * 128 + waveC * 64;
  int colL  = lane & 15;
  int rowHi = (lane >> 4) * 4;
  #pragma unroll
  for (int m = 0; m < 4; ++m)
    #pragma unroll
    for (int r = 0; r < 4; ++r) {
      int h = hb + m * 16 + rowHi + r;
      float ub = up_b[h], sb = sal_b[h];
      #pragma unroll
      for (int n = 0; n < 4; ++n) { accU[m][n][r] += ub; accS[m][n][r] += sb; }
    }

  // Block max of sal
  float lm = -INFINITY;
  #pragma unroll
  for (int m = 0; m < 4; ++m)
    #pragma unroll
    for (int n = 0; n < 4; ++n)
      #pragma unroll
      for (int r = 0; r < 4; ++r) lm = fmaxf(lm, accS[m][n][r]);
  for (int o = 32; o; o >>= 1) lm = fmaxf(lm, __shfl_xor(lm, o));
  if (lane == 0) redA[wave] = lm;
  __syncthreads();
  float M = fmaxf(fmaxf(redA[0], redA[1]), fmaxf(redA[2], redA[3]));
  float ls = 0.0f;
  #pragma unroll
  for (int m = 0; m < 4; ++m)
    #pragma unroll
    for (int n = 0; n < 4; ++n)
      #pragma unroll
      for (int r = 0; r < 4; ++r) ls += __expf(accS[m][n][r] - M);
  for (int o = 32; o; o >>= 1) ls += __shfl_xor(ls, o);
  if (lane == 0) redB[wave] = ls;
  __syncthreads();
  if (tid == 0)
    partials[b * 128 + blockIdx.x] = make_float2(M, redB[0] + redB[1] + redB[2] + redB[3]);

  // Histogram of bf16-rounded keys (reuse tile LDS); store u8 coarse bin
  unsigned int* hist = (unsigned int*)smem;
  for (int i = tid; i < NBINS; i += 256) hist[i] = 0;
  __syncthreads();
  unsigned char* keysB = keys8 + (size_t)b * HT;
  #pragma unroll
  for (int m = 0; m < 4; ++m)
    #pragma unroll
    for (int n = 0; n < 4; ++n)
      #pragma unroll
      for (int r = 0; r < 4; ++r) {
        float sig = accU[m][n][r];
        float sal = accS[m][n][r];
        float key = (sig > 0.0f) ? (__logf(sig) + sal) : -INFINITY;
        unsigned short kb16 = f2bf(key);
        int bin = key_bin(bf2f(kb16));
        int h = hb + m * 16 + rowHi + r;
        int t = tb + n * 16 + colL;
        keysB[(size_t)h * T_ + t] = (unsigned char)(bin >> 4);
        atomicAdd(&hist[bin], 1u);
      }
  __syncthreads();
  unsigned int* gh = ghist + b * NBINS;
  for (int i = tid; i < NBINS; i += 256) {
    unsigned int cv = hist[i];
    if (cv) atomicAdd(&gh[i], cv);
  }
}

// ---------- Pass B: per-batch M/S reduce + histogram threshold (parallel) ----------
__global__ void k_reduce(const float2* __restrict__ partials,
                         const unsigned int* __restrict__ ghist,
                         float* __restrict__ Mv, float* __restrict__ Sv,
                         int* __restrict__ thetaBin) {
  int b = blockIdx.x; int tid = threadIdx.x; int lane = tid & 63;
  __shared__ float sm[128], ss[128];
  __shared__ unsigned int hloc[NBINS];
  __shared__ unsigned int segsum[256];
  __shared__ float redM[2], redS[2];
  if (tid < 128) { float2 p = partials[b * 128 + tid]; sm[tid] = p.x; ss[tid] = p.y; }
  const unsigned int* gh = ghist + b * NBINS;
  int hi = 4095 - 16 * tid;
  unsigned int seg = 0;
  #pragma unroll
  for (int k = 0; k < 16; ++k) { unsigned int c = gh[hi - k]; hloc[hi - k] = c; seg += c; }
  segsum[tid] = seg;
  __syncthreads();
  if (tid < 128) {
    float m = sm[tid];
    for (int o = 32; o; o >>= 1) m = fmaxf(m, __shfl_xor(m, o));
    if (lane == 0) redM[tid >> 6] = m;
  }
  __syncthreads();
  float M = fmaxf(redM[0], redM[1]);
  if (tid < 128) {
    float s = ss[tid] * __expf(sm[tid] - M);
    for (int o = 32; o; o >>= 1) s += __shfl_xor(s, o);
    if (lane == 0) redS[tid >> 6] = s;
  }
  __syncthreads();
  if (tid == 0) {
    Mv[b] = M; Sv[b] = redS[0] + redS[1];
    unsigned int acc = 0; int theta = 1; int sidx = 0;
    while (sidx < 256 && acc + segsum[sidx] < KSP) { acc += segsum[sidx]; ++sidx; }
    if (sidx < 256) {
      int h2 = 4095 - 16 * sidx;
      for (int k = 0; k < 16; ++k) {
        acc += hloc[h2 - k];
        if (acc >= KSP) { theta = h2 - k; break; }
      }
    }
    theta -= MARGIN; if (theta < 1) theta = 1;
    thetaBin[b] = theta;
  }
}

// ---------- Pass C: collect candidates from u8 bins (block scan + 1 atomic/block) ----------
__global__ void k_collect(const unsigned char* __restrict__ keys8,
                          const int* __restrict__ thetaBin,
                          unsigned int* __restrict__ cnt,
                          unsigned int* __restrict__ cand) {
  __shared__ unsigned int wtot[4], wbase[4];
  int tid = threadIdx.x;
  int lane = tid & 63, wave = tid >> 6;
  size_t blockBase = (size_t)blockIdx.x * 8192;
  int b = (int)(blockBase >> 21);
  unsigned int localBase = (unsigned int)(blockBase & (HT - 1));
  unsigned int thetaU8 = (unsigned int)(thetaBin[b] >> 4);
  const unsigned char* kb = keys8 + blockBase;

  uint4 v[2];
  #pragma unroll
  for (int j = 0; j < 2; ++j) v[j] = *(const uint4*)(kb + j * 4096 + tid * 16);

  unsigned int mask = 0, mycnt = 0;
  #pragma unroll
  for (int j = 0; j < 2; ++j) {
    unsigned int ww[4] = {v[j].x, v[j].y, v[j].z, v[j].w};
    #pragma unroll
    for (int q = 0; q < 4; ++q) {
      #pragma unroll
      for (int k = 0; k < 4; ++k) {
        unsigned int bv = (ww[q] >> (8 * k)) & 0xFFu;
        if (bv >= thetaU8) { mask |= 1u << (j * 16 + q * 4 + k); ++mycnt; }
      }
    }
  }

  unsigned int pre = mycnt;
  #pragma unroll
  for (int o = 1; o < 64; o <<= 1) {
    unsigned int t = __shfl_up(pre, o);
    if (lane >= o) pre += t;
  }
  unsigned int myExcl = pre - mycnt;
  if (lane == 63) wtot[wave] = pre;
  __syncthreads();
  if (tid == 0) {
    unsigned int tot = wtot[0] + wtot[1] + wtot[2] + wtot[3];
    unsigned int gbase = tot ? atomicAdd(&cnt[b], tot) : 0u;
    unsigned int acc = gbase;
    #pragma unroll
    for (int w = 0; w < 4; ++w) { wbase[w] = acc; acc += wtot[w]; }
  }
  __syncthreads();
  unsigned int pos = wbase[wave] + myExcl;
  unsigned int m = mask;
  while (m) {
    int i = __ffs(m) - 1; m &= m - 1;
    int j = i >> 4, rq = i & 15;
    unsigned int idx = localBase + (unsigned int)(j * 4096 + tid * 16 + rq);
    if (pos < CAP) cand[b * CAP + pos] = idx;
    ++pos;
  }
}

// ---------- Pass D1: exact fp64 recompute, one WAVE per candidate (no barriers) ----------
__global__ void k_refine(const float* __restrict__ xT32, const float* __restrict__ wup,
                         const float* __restrict__ wsal, const float* __restrict__ up_b,
                         const float* __restrict__ sal_b, const unsigned int* __restrict__ cnt,
                         const unsigned int* __restrict__ cand, double* __restrict__ keyd) {
  int b = blockIdx.y;
  unsigned int nc = cnt[b];
  int n = nc < CAP ? (int)nc : CAP;
  int lane = threadIdx.x & 63;
  int wid = blockIdx.x * 4 + (threadIdx.x >> 6);   // 0..511 waves per batch
  for (int slot = wid; slot < n; slot += 512) {
    unsigned int idx = cand[b * CAP + slot];
    int h = (int)(idx >> 9), t = (int)(idx & 511);
    const float4* wv = (const float4*)(wup  + (size_t)h * C_);
    const float4* sv = (const float4*)(wsal + (size_t)h * C_);
    const float4* xv = (const float4*)(xT32 + ((size_t)b * T_ + t) * C_);
    double du = 0.0, ds = 0.0;
    #pragma unroll
    for (int j = 0; j < 4; ++j) {
      float4 w4 = wv[lane + 64 * j];
      float4 s4 = sv[lane + 64 * j];
      float4 x4 = xv[lane + 64 * j];
      du += (double)w4.x * x4.x + (double)w4.y * x4.y + (double)w4.z * x4.z + (double)w4.w * x4.w;
      ds += (double)s4.x * x4.x + (double)s4.y * x4.y + (double)s4.z * x4.z + (double)s4.w * x4.w;
    }
    #pragma unroll
    for (int o = 32; o; o >>= 1) { du += __shfl_xor(du, o); ds += __shfl_xor(ds, o); }
    if (lane == 0) {
      double sig = du + (double)up_b[h];
      double sal = ds + (double)sal_b[h];
      keyd[b * CAP + slot] = (sig > 0.0) ? (log(sig) + sal) : -1e300;
    }
  }
}

// ---------- Pass D2: bitonic-sort top-128 selection + scatter outputs ----------
__launch_bounds__(256, 1)
__global__ void k_final(const double* __restrict__ keyd, const unsigned int* __restrict__ cnt,
                        const unsigned int* __restrict__ cand, const float* __restrict__ Mv,
                        const float* __restrict__ Sv, float* __restrict__ out) {
  int b = blockIdx.x; int tid = threadIdx.x;
  unsigned int nc = cnt[b];
  int n = nc < CAP ? (int)nc : CAP;
  int L = 256;
  while (L < n) L <<= 1;

  __shared__ unsigned long long sk[CAP];  // ~d2u(key): ascending sk == descending key
  __shared__ unsigned int sid[CAP];
  for (int i = tid; i < L; i += 256) {
    if (i < n) { sk[i] = ~d2u(keyd[b * CAP + i]); sid[i] = cand[b * CAP + i]; }
    else       { sk[i] = 0xFFFFFFFFFFFFFFFFull;   sid[i] = 0xFFFFFFFFu; }
  }
  for (int size = 2; size <= L; size <<= 1) {
    for (int stride = size >> 1; stride > 0; stride >>= 1) {
      __syncthreads();
      for (int i = tid; i < (L >> 1); i += 256) {
        int ix = 2 * i - (i & (stride - 1));
        int iy = ix + stride;
        bool asc = ((ix & size) == 0);
        unsigned long long ka = sk[ix], kb = sk[iy];
        unsigned int ia = sid[ix], ib = sid[iy];
        bool aLessB = (ka < kb) || (ka == kb && ia < ib);
        if (asc != aLessB) { sk[ix] = kb; sk[iy] = ka; sid[ix] = ib; sid[iy] = ia; }
      }
    }
  }
  __syncthreads();
  if (tid < KSP) {
    unsigned int idx = sid[tid];
    if (idx != 0xFFFFFFFFu) {
      double key = u2d(~sk[tid]);
      double val = exp(key - (double)Mv[b]) / (double)Sv[b];
      float vf = (float)val;
      int h = (int)(idx >> 9), t = (int)(idx & 511);
      out[(size_t)b * HT + idx] = vf;                                             // sparse
      out[(size_t)B_ * HT + ((size_t)b * KSP + tid) * H_ + h] = vf;               // packed
      out[(size_t)B_ * HT + (size_t)B_ * KSP * H_ + ((size_t)b * KSP + tid) * T_ + t] = 1.0f; // time_oh
    }
  }
}

extern "C" void kernel_launch(void* const* d_in, const int* in_sizes, int n_in,
                              void* d_out, int out_size, void* d_ws, size_t ws_size,
                              hipStream_t stream) {
  const float* x    = (const float*)d_in[0];
  const float* wup  = (const float*)d_in[1];
  const float* upb  = (const float*)d_in[2];
  const float* wsal = (const float*)d_in[3];
  const float* salb = (const float*)d_in[4];
  float* out = (float*)d_out;

  // Small scratch always at the front of d_ws.
  char* wb = (char*)d_ws;
  unsigned int* ghist  = (unsigned int*)wb;            // 262,144 B
  unsigned int* cnt    = (unsigned int*)(wb + 262144); // (ghist+cnt zeroed by k_pre)
  int*          thetaB = (int*)(wb + 262208);
  float*        Mv     = (float*)(wb + 262272);
  float*        Sv     = (float*)(wb + 262336);
  float2*       parts  = (float2*)(wb + 262400);       // 16,384 B
  unsigned int* cand   = (unsigned int*)(wb + 278784); // 262,144 B
  double*       keyd   = (double*)(wb + 540928);       // 524,288 B -> small region ends 1,065,216

  // Big scratch: in d_ws if it fits (then d_out is pure output, zeroed by k_gemm),
  // else inside d_out (R8 fallback, zeroed by memset after last scratch read).
  const size_t SMALL_END = 1065216;
  const size_t BIG_BYTES = 100663296;
  bool wsPath = (ws_size >= SMALL_END + BIG_BYTES);
  char* big = wsPath ? (wb + SMALL_END) : (char*)d_out;

  unsigned char*  keys8  = (unsigned char*)(big);                // 33,554,432 B
  float*          xT32   = (float*)(big + 33554432);             // 33,554,432 B
  unsigned short* xT16   = (unsigned short*)(big + 67108864);    // 16,777,216 B
  unsigned short* wup16  = (unsigned short*)(big + 83886080);    //  8,388,608 B
  unsigned short* wsal16 = (unsigned short*)(big + 92274688);    //  8,388,608 B (ends 100,663,296)

  k_pre<<<10497, 256, 0, stream>>>(x, wup, wsal, wup16, wsal16, xT32, xT16, ghist);
  k_gemm<<<dim3(128, B_), 256, 0, stream>>>(wup16, wsal16, xT16, upb, salb, keys8, parts, ghist,
                                            wsPath ? (float4*)d_out : (float4*)0);
  k_reduce<<<B_, 256, 0, stream>>>(parts, ghist, Mv, Sv, thetaB);
  k_collect<<<4096, 256, 0, stream>>>(keys8, thetaB, cnt, cand);
  k_refine<<<dim3(128, B_), 256, 0, stream>>>(xT32, wup, wsal, upb, salb, cnt, cand, keyd);
  if (!wsPath) { (void)hipMemsetAsync(d_out, 0, (size_t)out_size * 4, stream); }
  k_final<<<B_, 256, 0, stream>>>(keyd, cnt, cand, Mv, Sv, out);
}